// Round 18
// baseline (155.328 us; speedup 1.0000x reference)
//
#include <hip/hip_runtime.h>
#include <stdint.h>
#include <stddef.h>

typedef int v4i __attribute__((ext_vector_type(4)));

#define GLOAD_LDS16(g, l) __builtin_amdgcn_global_load_lds( \
    (const __attribute__((address_space(1))) void*)(g),     \
    (__attribute__((address_space(3))) void*)(l), 16, 0, 0)

// ---------------------------------------------------------------------------
// Quantize rows of length 2048 for BOTH x and w in one dispatch (R17-verified):
// blocks [0, nx4) -> x rows (floor 1e-12); rest -> w rows (floor 1e-8/127).
// scale = max(amax/127, floorv); q = clip(rint(v/scale), -128, 127)
// ---------------------------------------------------------------------------
__device__ __forceinline__ int pack4(float4 f, float s) {
    int a = (int)rintf(f.x / s); a = a < -128 ? -128 : (a > 127 ? 127 : a);
    int b = (int)rintf(f.y / s); b = b < -128 ? -128 : (b > 127 ? 127 : b);
    int c = (int)rintf(f.z / s); c = c < -128 ? -128 : (c > 127 ? 127 : c);
    int d = (int)rintf(f.w / s); d = d < -128 ? -128 : (d > 127 ? 127 : d);
    return (a & 255) | ((b & 255) << 8) | ((c & 255) << 16) | ((d & 255) << 24);
}

__global__ __launch_bounds__(256) void quant_both_2048(
    const float* __restrict__ x, signed char* __restrict__ xq,
    float* __restrict__ xs,
    const float* __restrict__ w, signed char* __restrict__ wq,
    float* __restrict__ wsc, int nx4)
{
    const int lane = threadIdx.x & 63;
    const bool isx = ((int)blockIdx.x < nx4);
    const int rb   = isx ? blockIdx.x : (blockIdx.x - nx4);
    const int row  = rb * 4 + (threadIdx.x >> 6);
    const float* in = isx ? x : w;
    signed char* q  = isx ? xq : wq;
    float* scales   = isx ? xs : wsc;
    const float floorv = isx ? 1e-12f : (1e-8f / 127.0f);
    const float* rp = in + (size_t)row * 2048;

    float4 v[8];
#pragma unroll
    for (int j = 0; j < 2; ++j) {
        const float4* p = (const float4*)(rp + j * 1024 + lane * 16);
#pragma unroll
        for (int i = 0; i < 4; ++i) v[j * 4 + i] = p[i];
    }
    float am = 0.0f;
#pragma unroll
    for (int i = 0; i < 8; ++i) {
        am = fmaxf(am, fabsf(v[i].x));
        am = fmaxf(am, fabsf(v[i].y));
        am = fmaxf(am, fabsf(v[i].z));
        am = fmaxf(am, fabsf(v[i].w));
    }
#pragma unroll
    for (int off = 32; off; off >>= 1) am = fmaxf(am, __shfl_xor(am, off));
    const float s = fmaxf(am / 127.0f, floorv);

#pragma unroll
    for (int j = 0; j < 2; ++j) {
        int4 pk;
        pk.x = pack4(v[j * 4 + 0], s);
        pk.y = pack4(v[j * 4 + 1], s);
        pk.z = pack4(v[j * 4 + 2], s);
        pk.w = pack4(v[j * 4 + 3], s);
        *(int4*)(q + (size_t)row * 2048 + j * 1024 + lane * 16) = pk;
    }
    if (lane == 0) scales[row] = s;
}

// ---------------------------------------------------------------------------
// int8 GEMM — BARRIER-FREE private-staging waves. Every prior structure was
// collectively gated once per K-tile (26-33% MfmaUtil band). Here each wave
// stages a PRIVATE copy of exactly the A/B rows it reads -> zero cross-wave
// deps -> ZERO barriers in the K-loop; per-wave counted vmcnt on its own
// stages; WAR enforced by single-wave program order (in-order ds queue +
// compiler lgkm on fragment consumption).
// 128x128 block, 256 thr = 4 waves (2M x 2N), wave 64x64 via 4x4 frags of
// mfma_i32_16x16x64_i8 (layouts verified R1-R17). Private ring-4 x 8KB =
// 32 KB/wave, 128 KB/block -> 1 block/CU, 1 wave/SIMD, ~512-VGPR budget:
// register double-buffering of fragments is spill-proof here (fixes R14).
// Depth-3 prefetch: stage t+3 during t; steady vmcnt(16) drains ST8(t+1)
// (8/0 in tail; never blind-0 while stages remain). Duplicate staging bytes
// are L2 hits (lines just fetched by the sibling wave).
// Swizzle (verified): stage lane l -> row (l>>2), slot l&3 holds global
// chunk (l&3)^((row>>1)&3); read slot = ko ^ ((rl>>1)&3).
// ---------------------------------------------------------------------------
__global__ __launch_bounds__(256, 1) void gemm_i8_nobar(
    const signed char* __restrict__ xq, const signed char* __restrict__ wq,
    const float* __restrict__ xs, const float* __restrict__ ws,
    const float* __restrict__ bias, float* __restrict__ out, int K)
{
    __shared__ __align__(16) signed char lds[131072]; // 4 waves x (4 bufs x 8KB)

    const int tid  = threadIdx.x;
    const int lane = tid & 63;
    const int wid  = tid >> 6;        // 0..3
    const int wm   = wid >> 1;        // 0..1
    const int wn   = wid & 1;         // 0..1

    const int nwg  = gridDim.x * gridDim.y;
    int orig = blockIdx.y * gridDim.x + blockIdx.x;
    int swz  = ((nwg & 7) == 0) ? ((orig & 7) * (nwg >> 3) + (orig >> 3)) : orig;
    const int brow = (swz / gridDim.x) * 128;
    const int bcol = (swz % gridDim.x) * 128;

    signed char* ldsW = lds + wid * 32768;   // private region

    // staging: instr i covers wave-local rows 16i..16i+15; lane l -> row
    // 16i+(l>>2), slot l&3; source pre-swizzled so slot c holds chunk
    // c ^ ((row>>1)&3); ((16i+(l>>2))>>1)&3 == (l>>3)&3 (16i ≡ 0 mod 8).
    const int gch = (((lane & 3) ^ ((lane >> 3) & 3)) << 4);
    const signed char* gAl = xq + (size_t)(brow + wm * 64 + (lane >> 2)) * K + gch;
    const signed char* gBl = wq + (size_t)(bcol + wn * 64 + (lane >> 2)) * K + gch;

#define ST8(tt, bb) do {                                                              \
    GLOAD_LDS16(gAl + (size_t)(tt) * 64,                  ldsW + (bb) * 8192 + (lane << 4));         \
    GLOAD_LDS16(gAl + (size_t)16 * K + (size_t)(tt) * 64, ldsW + (bb) * 8192 + 1024 + (lane << 4));  \
    GLOAD_LDS16(gAl + (size_t)32 * K + (size_t)(tt) * 64, ldsW + (bb) * 8192 + 2048 + (lane << 4));  \
    GLOAD_LDS16(gAl + (size_t)48 * K + (size_t)(tt) * 64, ldsW + (bb) * 8192 + 3072 + (lane << 4));  \
    GLOAD_LDS16(gBl + (size_t)(tt) * 64,                  ldsW + (bb) * 8192 + 4096 + (lane << 4));  \
    GLOAD_LDS16(gBl + (size_t)16 * K + (size_t)(tt) * 64, ldsW + (bb) * 8192 + 5120 + (lane << 4));  \
    GLOAD_LDS16(gBl + (size_t)32 * K + (size_t)(tt) * 64, ldsW + (bb) * 8192 + 6144 + (lane << 4));  \
    GLOAD_LDS16(gBl + (size_t)48 * K + (size_t)(tt) * 64, ldsW + (bb) * 8192 + 7168 + (lane << 4));  \
} while (0)

    const int rl   = lane & 15;
    const int ko   = lane >> 4;
    const int slot = ((ko ^ ((rl >> 1) & 3)) << 4);

#define FRAG_A(bb, m) (*(const v4i*)(ldsW + (bb) * 8192 + ((m) * 16 + rl) * 64 + slot))
#define FRAG_B(bb, n) (*(const v4i*)(ldsW + (bb) * 8192 + 4096 + ((n) * 16 + rl) * 64 + slot))

#define MFMA16(A0, A1, A2, A3, B0, B1, B2, B3)                                              \
    do {                                                                                    \
        acc[0][0] = __builtin_amdgcn_mfma_i32_16x16x64_i8(A0, B0, acc[0][0], 0, 0, 0);      \
        acc[0][1] = __builtin_amdgcn_mfma_i32_16x16x64_i8(A0, B1, acc[0][1], 0, 0, 0);      \
        acc[0][2] = __builtin_amdgcn_mfma_i32_16x16x64_i8(A0, B2, acc[0][2], 0, 0, 0);      \
        acc[0][3] = __builtin_amdgcn_mfma_i32_16x16x64_i8(A0, B3, acc[0][3], 0, 0, 0);      \
        acc[1][0] = __builtin_amdgcn_mfma_i32_16x16x64_i8(A1, B0, acc[1][0], 0, 0, 0);      \
        acc[1][1] = __builtin_amdgcn_mfma_i32_16x16x64_i8(A1, B1, acc[1][1], 0, 0, 0);      \
        acc[1][2] = __builtin_amdgcn_mfma_i32_16x16x64_i8(A1, B2, acc[1][2], 0, 0, 0);      \
        acc[1][3] = __builtin_amdgcn_mfma_i32_16x16x64_i8(A1, B3, acc[1][3], 0, 0, 0);      \
        acc[2][0] = __builtin_amdgcn_mfma_i32_16x16x64_i8(A2, B0, acc[2][0], 0, 0, 0);      \
        acc[2][1] = __builtin_amdgcn_mfma_i32_16x16x64_i8(A2, B1, acc[2][1], 0, 0, 0);      \
        acc[2][2] = __builtin_amdgcn_mfma_i32_16x16x64_i8(A2, B2, acc[2][2], 0, 0, 0);      \
        acc[2][3] = __builtin_amdgcn_mfma_i32_16x16x64_i8(A2, B3, acc[2][3], 0, 0, 0);      \
        acc[3][0] = __builtin_amdgcn_mfma_i32_16x16x64_i8(A3, B0, acc[3][0], 0, 0, 0);      \
        acc[3][1] = __builtin_amdgcn_mfma_i32_16x16x64_i8(A3, B1, acc[3][1], 0, 0, 0);      \
        acc[3][2] = __builtin_amdgcn_mfma_i32_16x16x64_i8(A3, B2, acc[3][2], 0, 0, 0);      \
        acc[3][3] = __builtin_amdgcn_mfma_i32_16x16x64_i8(A3, B3, acc[3][3], 0, 0, 0);      \
    } while (0)

    v4i acc[4][4] = {};

    // ---- prologue: stage tiles 0,1,2 (24 vmem); drain ST8(0); read frags(0)
    ST8(0, 0);
    ST8(1, 1);
    ST8(2, 2);
    asm volatile("s_waitcnt vmcnt(16)" ::: "memory");
    v4i cA0 = FRAG_A(0, 0), cA1 = FRAG_A(0, 1), cA2 = FRAG_A(0, 2), cA3 = FRAG_A(0, 3);
    v4i cB0 = FRAG_B(0, 0), cB1 = FRAG_B(0, 1), cB2 = FRAG_B(0, 2), cB3 = FRAG_B(0, 3);
    v4i nA0, nA1, nA2, nA3, nB0, nB1, nB2, nB3;

    const int NT = K >> 6;   // 32 (even)
    for (int t = 0; t < NT; t += 2) {
        // ---- even tile t: consume c*, prefetch frags(t+1) into n*
        if (t + 3 < NT) {
            ST8(t + 3, (t + 3) & 3);
            asm volatile("s_waitcnt vmcnt(16)" ::: "memory");  // ST8(t+1) done
        } else {
            asm volatile("s_waitcnt vmcnt(0)" ::: "memory");   // t = NT-2 tail
        }
        {
            const int nb = (t + 1) & 3;
            nA0 = FRAG_A(nb, 0); nA1 = FRAG_A(nb, 1);
            nA2 = FRAG_A(nb, 2); nA3 = FRAG_A(nb, 3);
            nB0 = FRAG_B(nb, 0); nB1 = FRAG_B(nb, 1);
            nB2 = FRAG_B(nb, 2); nB3 = FRAG_B(nb, 3);
        }
        MFMA16(cA0, cA1, cA2, cA3, cB0, cB1, cB2, cB3);

        // ---- odd tile t+1: consume n*, prefetch frags(t+2) into c*
        if (t + 4 < NT) {
            ST8(t + 4, (t + 4) & 3);
            asm volatile("s_waitcnt vmcnt(16)" ::: "memory");  // ST8(t+2) done
        } else if (t + 2 < NT) {
            asm volatile("s_waitcnt vmcnt(8)" ::: "memory");   // t = NT-4 tail
        }
        if (t + 2 < NT) {
            const int cb = (t + 2) & 3;
            cA0 = FRAG_A(cb, 0); cA1 = FRAG_A(cb, 1);
            cA2 = FRAG_A(cb, 2); cA3 = FRAG_A(cb, 3);
            cB0 = FRAG_B(cb, 0); cB1 = FRAG_B(cb, 1);
            cB2 = FRAG_B(cb, 2); cB3 = FRAG_B(cb, 3);
        }
        MFMA16(nA0, nA1, nA2, nA3, nB0, nB1, nB2, nB3);
    }

    // ---- epilogue: C/D layout col = lane&15, row = (lane>>4)*4 + j
    const int rg = lane >> 4;
#pragma unroll
    for (int n = 0; n < 4; ++n) {
        const int col = bcol + wn * 64 + n * 16 + rl;
        const float wsc = ws[col];
        const float bv  = bias[col];
#pragma unroll
        for (int m = 0; m < 4; ++m) {
#pragma unroll
            for (int j = 0; j < 4; ++j) {
                const int row = brow + wm * 64 + m * 16 + rg * 4 + j;
                out[(size_t)row * 2048 + col] =
                    (float)acc[m][n][j] * xs[row] * wsc + bv;
            }
        }
    }
#undef ST8
#undef FRAG_A
#undef FRAG_B
#undef MFMA16
}

// ---------------------------------------------------------------------------
extern "C" void kernel_launch(void* const* d_in, const int* in_sizes, int n_in,
                              void* d_out, int out_size, void* d_ws, size_t ws_size,
                              hipStream_t stream) {
    const float* x    = (const float*)d_in[0];   // [B,N,D] = [4,4096,2048]
    const float* w    = (const float*)d_in[1];   // [O,D]   = [2048,2048]
    const float* bias = (const float*)d_in[2];   // [O]
    float* out = (float*)d_out;

    const int D = 2048;
    const int O = in_sizes[2];                   // 2048
    const int M = in_sizes[0] / D;               // 16384

    char* wsb = (char*)d_ws;
    signed char* xq  = (signed char*)wsb;
    signed char* wqp = (signed char*)(wsb + (size_t)M * D);
    float* xs  = (float*)(wsb + (size_t)M * D + (size_t)O * D);
    float* wsc = (float*)(wsb + (size_t)M * D + (size_t)O * D + (size_t)M * 4);

    quant_both_2048<<<(M + O) / 4, 256, 0, stream>>>(x, xq, xs, w, wqp, wsc, M / 4);

    dim3 grid(O / 128, M / 128);   // (16, 128) = 2048 blocks, %8 == 0
    gemm_i8_nobar<<<grid, 256, 0, stream>>>(xq, wqp, xs, wsc, bias, out, D);
}